// Round 12
// baseline (2110.629 us; speedup 1.0000x reference)
//
#include <hip/hip_runtime.h>
#include <hip/hip_bf16.h>
#include <cstdint>
#include <cstddef>

#define T_TOK 4096
#define DMODEL 2048
#define DFF 8192
#define NEXP 8
#define NPAIR (T_TOK * 2)

typedef __bf16 bf16_t;
typedef __bf16 bf16x8 __attribute__((ext_vector_type(8)));
typedef float fx4 __attribute__((ext_vector_type(4)));

__device__ __forceinline__ void gload16(const bf16_t* src, bf16_t* dst) {
    __builtin_amdgcn_global_load_lds(
        (const __attribute__((address_space(1))) uint32_t*)(src),
        (__attribute__((address_space(3))) uint32_t*)(dst), 16, 0, 0);
}

__device__ __forceinline__ bf16x8 pack8(const fx4 lo, const fx4 hi) {
    bf16x8 o;
    o[0] = (bf16_t)lo[0]; o[1] = (bf16_t)lo[1]; o[2] = (bf16_t)lo[2]; o[3] = (bf16_t)lo[3];
    o[4] = (bf16_t)hi[0]; o[5] = (bf16_t)hi[1]; o[6] = (bf16_t)hi[2]; o[7] = (bf16_t)hi[3];
    return o;
}

// ---------------- router ----------------
__global__ void router_kernel(const float* __restrict__ gating, int* __restrict__ counts,
                              int* __restrict__ tok_list, float* __restrict__ w_list) {
    int t = blockIdx.x * blockDim.x + threadIdx.x;
    if (t >= T_TOK) return;
    float l[NEXP];
    float mx = -1e30f;
#pragma unroll
    for (int e = 0; e < NEXP; e++) { l[e] = gating[t * NEXP + e]; mx = fmaxf(mx, l[e]); }
#pragma unroll
    for (int e = 0; e < NEXP; e++) { l[e] = __expf(l[e] - mx); }
    int e0 = 0; float p0 = l[0];
#pragma unroll
    for (int e = 1; e < NEXP; e++) { if (l[e] > p0) { p0 = l[e]; e0 = e; } }
    int e1 = -1; float p1 = -1.0f;
#pragma unroll
    for (int e = 0; e < NEXP; e++) { if (e != e0 && l[e] > p1) { p1 = l[e]; e1 = e; } }
    float inv = 1.0f / (p0 + p1);
    int s0 = atomicAdd(&counts[e0], 1);
    tok_list[e0 * T_TOK + s0] = t; w_list[e0 * T_TOK + s0] = p0 * inv;
    int s1 = atomicAdd(&counts[e1], 1);
    tok_list[e1 * T_TOK + s1] = t; w_list[e1 * T_TOK + s1] = p1 * inv;
}

__global__ void scan_kernel(const int* __restrict__ counts, int* __restrict__ offsets) {
    if (threadIdx.x == 0 && blockIdx.x == 0) {
        int acc = 0;
        for (int e = 0; e < NEXP; e++) { offsets[e] = acc; acc += counts[e]; }
        offsets[NEXP] = acc;
    }
}

// ---------------- x fp32 -> bf16 ----------------
__global__ void cvt_x_kernel(const float* __restrict__ x, bf16_t* __restrict__ xb) {
    int i = blockIdx.x * blockDim.x + threadIdx.x;
    const fx4* src = (const fx4*)x;
    fx4 v0 = src[2 * i], v1 = src[2 * i + 1];
    *(bf16x8*)(xb + (size_t)i * 8) = pack8(v0, v1);
}

#define PHASE_SYNC()                                        \
    __builtin_amdgcn_s_barrier();                           \
    asm volatile("s_waitcnt lgkmcnt(0)" ::: "memory");      \
    __builtin_amdgcn_sched_barrier(0);

// ================= gate_up GEMM — 8-phase (m201 port) =================
// 512 thr = 8 waves (2M x 4N). tile: BM=256 tok, W-tile 256 rows (128 g + 128 u) = 128 h-cols.
// per-wave output 128 x (32g+32u): accg[8][2]+accu[8][2] = 128 VGPR. BK=64, NT=32.
// LDS 128 KB: A dbuf 2x32K (gload_lds, pre-swz src) + W dbuf 2x32K (reg-staged fp32->bf16, T14).
// Per K-tile: 4 phases {reads -> barrier -> lgkm(0) -> 16 MFMA -> barrier}; stage issued P1,
// W write-late in P4 (implicit vmcnt = counted-by-construction drain at end of compute).
// dispatch: idx=(e,ygrp,mslot,q): q=XCD, panel y=q+8*ygrp (64 panels of 128 h-cols).
__global__ __launch_bounds__(512, 2) void gateup_kernel(
    const bf16_t* __restrict__ xb, const float* __restrict__ gup,
    const int* __restrict__ counts, const int* __restrict__ offsets,
    const int* __restrict__ tok_list, bf16_t* __restrict__ h_buf)
{
    const int idx = blockIdx.x;
    const int q = idx & 7;
    const int mslot = (idx >> 3) & 15;
    const int g2 = idx >> 7;             // 0..63
    const int e = g2 >> 3;
    const int cnt = counts[e];
    const int mbase = mslot * 256;
    if (mbase >= cnt) return;
    const int y = q + 8 * (g2 & 7);      // panel 0..63
    const int nb = y * 128;              // h-col base
    const int off_e = offsets[e];

    __shared__ __align__(16) bf16_t lds_a[2][256 * 64];   // 2 x 32 KB
    __shared__ __align__(16) bf16_t lds_w[2][256 * 64];   // 2 x 32 KB (rows 0-127 g, 128-255 u)

    const int tid = threadIdx.x;
    const int lane = tid & 63;
    const int w = tid >> 6;
    const int wm = (w >> 2) * 128;       // M-half of wave
    const int wn = (w & 3) * 32;         // 32 g-rows + 32 u-rows per wave
    const int l15 = lane & 15;
    const int l4 = lane >> 4;

    // A staging: 4 gload16/wave covers 32 of 256 rows
    const bf16_t* a_src[4];
    int a_doff[4];
#pragma unroll
    for (int j = 0; j < 4; j++) {
        int row = (w * 4 + j) * 8 + (lane >> 3);
        int c8 = (lane & 7) ^ (row & 7);
        int slot = mbase + row;
        int tok = tok_list[e * T_TOK + (slot < cnt ? slot : cnt - 1)];
        a_src[j] = xb + (size_t)tok * DMODEL + c8 * 8;
        a_doff[j] = (w * 4 + j) * 512;
    }
    // W staging: 2048 chunks (256 rows x 8), 4/thread; fp32 -> reg -> bf16 -> swz ds_write
    const float* w_src[4];
    int w_st[4];
    const float* gup_e = gup + (size_t)e * (2 * DFF) * DMODEL;
#pragma unroll
    for (int c4 = 0; c4 < 4; c4++) {
        int cid = c4 * 512 + tid;
        int row = cid >> 3, c = cid & 7;
        int grow = (row < 128) ? (nb + row) : (DFF + nb + (row - 128));
        w_src[c4] = gup_e + (size_t)grow * DMODEL + c * 8;
        w_st[c4] = row * 64 + ((c ^ (row & 7)) * 8);
    }

    fx4 accg[8][2] = {};
    fx4 accu[8][2] = {};
    fx4 wreg[8];

    const int NT = DMODEL / 64;

    // prologue: stage tile 0 into buf 0
#pragma unroll
    for (int j = 0; j < 4; j++) gload16(a_src[j], &lds_a[0][a_doff[j]]);
#pragma unroll
    for (int c4 = 0; c4 < 4; c4++) {
        wreg[2 * c4]     = *(const fx4*)(w_src[c4]);
        wreg[2 * c4 + 1] = *(const fx4*)(w_src[c4] + 4);
    }
#pragma unroll
    for (int c4 = 0; c4 < 4; c4++)
        *(bf16x8*)(&lds_w[0][w_st[c4]]) = pack8(wreg[2 * c4], wreg[2 * c4 + 1]);
    asm volatile("s_waitcnt vmcnt(0) lgkmcnt(0)" ::: "memory");
    __builtin_amdgcn_s_barrier();

    for (int t = 0; t < NT; ++t) {
        const int cur = t & 1;
        const int nxt = cur ^ 1;
        const bf16_t* A = lds_a[cur];
        const bf16_t* Wl = lds_w[cur];
        const bool pre = (t + 1 < NT);

        bf16x8 af[2][4], gfr[2][2], ufr[2][2];

        // ---- P1: issue stage(t+1); read A-mh0 + gf; MFMA mh0 x g ----
        if (pre) {
#pragma unroll
            for (int j = 0; j < 4; j++)
                gload16(a_src[j] + (t + 1) * 64, &lds_a[nxt][a_doff[j]]);
#pragma unroll
            for (int c4 = 0; c4 < 4; c4++) {
                wreg[2 * c4]     = *(const fx4*)(w_src[c4] + (t + 1) * 64);
                wreg[2 * c4 + 1] = *(const fx4*)(w_src[c4] + (t + 1) * 64 + 4);
            }
        }
#pragma unroll
        for (int kp = 0; kp < 2; kp++) {
            const int ke = kp * 4 + l4;
#pragma unroll
            for (int m = 0; m < 4; m++) {
                int r = wm + m * 16 + l15;
                af[kp][m] = *(const bf16x8*)(&A[r * 64 + ((ke ^ (r & 7)) * 8)]);
            }
#pragma unroll
            for (int n = 0; n < 2; n++) {
                int r = wn + n * 16 + l15;
                gfr[kp][n] = *(const bf16x8*)(&Wl[r * 64 + ((ke ^ (r & 7)) * 8)]);
            }
        }
        PHASE_SYNC();
        __builtin_amdgcn_s_setprio(1);
#pragma unroll
        for (int kp = 0; kp < 2; kp++)
#pragma unroll
            for (int m = 0; m < 4; m++)
#pragma unroll
                for (int n = 0; n < 2; n++)
                    accg[m][n] = __builtin_amdgcn_mfma_f32_16x16x32_bf16(af[kp][m], gfr[kp][n], accg[m][n], 0, 0, 0);
        __builtin_amdgcn_s_setprio(0);
        __builtin_amdgcn_s_barrier();

        // ---- P2: read uf; MFMA mh0 x u ----
#pragma unroll
        for (int kp = 0; kp < 2; kp++) {
            const int ke = kp * 4 + l4;
#pragma unroll
            for (int n = 0; n < 2; n++) {
                int r = 128 + wn + n * 16 + l15;
                ufr[kp][n] = *(const bf16x8*)(&Wl[r * 64 + ((ke ^ (r & 7)) * 8)]);
            }
        }
        PHASE_SYNC();
        __builtin_amdgcn_s_setprio(1);
#pragma unroll
        for (int kp = 0; kp < 2; kp++)
#pragma unroll
            for (int m = 0; m < 4; m++)
#pragma unroll
                for (int n = 0; n < 2; n++)
                    accu[m][n] = __builtin_amdgcn_mfma_f32_16x16x32_bf16(af[kp][m], ufr[kp][n], accu[m][n], 0, 0, 0);
        __builtin_amdgcn_s_setprio(0);
        __builtin_amdgcn_s_barrier();

        // ---- P3: read A-mh1; MFMA mh1 x g ----
#pragma unroll
        for (int kp = 0; kp < 2; kp++) {
            const int ke = kp * 4 + l4;
#pragma unroll
            for (int m = 0; m < 4; m++) {
                int r = wm + 64 + m * 16 + l15;
                af[kp][m] = *(const bf16x8*)(&A[r * 64 + ((ke ^ (r & 7)) * 8)]);
            }
        }
        PHASE_SYNC();
        __builtin_amdgcn_s_setprio(1);
#pragma unroll
        for (int kp = 0; kp < 2; kp++)
#pragma unroll
            for (int m = 0; m < 4; m++)
#pragma unroll
                for (int n = 0; n < 2; n++)
                    accg[4 + m][n] = __builtin_amdgcn_mfma_f32_16x16x32_bf16(af[kp][m], gfr[kp][n], accg[4 + m][n], 0, 0, 0);
        __builtin_amdgcn_s_setprio(0);
        __builtin_amdgcn_s_barrier();

        // ---- P4: MFMA mh1 x u; write-late W(t+1) ----
        __builtin_amdgcn_s_setprio(1);
#pragma unroll
        for (int kp = 0; kp < 2; kp++)
#pragma unroll
            for (int m = 0; m < 4; m++)
#pragma unroll
                for (int n = 0; n < 2; n++)
                    accu[4 + m][n] = __builtin_amdgcn_mfma_f32_16x16x32_bf16(af[kp][m], ufr[kp][n], accu[4 + m][n], 0, 0, 0);
        __builtin_amdgcn_s_setprio(0);
        __builtin_amdgcn_sched_barrier(0);
        if (pre) {
#pragma unroll
            for (int c4 = 0; c4 < 4; c4++)
                *(bf16x8*)(&lds_w[nxt][w_st[c4]]) = pack8(wreg[2 * c4], wreg[2 * c4 + 1]);
        } else {
            asm volatile("s_waitcnt vmcnt(0)" ::: "memory");
        }
        asm volatile("s_waitcnt lgkmcnt(0)" ::: "memory");
        __builtin_amdgcn_s_barrier();
    }

    // epilogue: h = silu(g) * u -> bf16
    const int colbase = nb + wn + l15;
#pragma unroll
    for (int am = 0; am < 8; am++) {
        int rb = wm + (am >> 2) * 64 + (am & 3) * 16 + l4 * 4;
#pragma unroll
        for (int j = 0; j < 4; j++) {
            int slot = mbase + rb + j;
            if (slot < cnt) {
                size_t hrow = (size_t)(off_e + slot);
#pragma unroll
                for (int n = 0; n < 2; n++) {
                    float g = accg[am][n][j];
                    float u = accu[am][n][j];
                    float hv = g * u / (1.0f + __expf(-g));
                    h_buf[hrow * DFF + colbase + n * 16] = (bf16_t)hv;
                }
            }
        }
    }
}

// ================= down GEMM — 8-phase (same skeleton) =================
// 512 thr = 8 waves (2M x 4N). tile: BM=256 pairs x BN=256 out-cols, BK=64, NT=128.
// per-wave 128 x 64: acc[8][4] = 128 VGPR. dispatch: idx=(e,mslot,q): panel = q (8 x 256 cols).
__global__ __launch_bounds__(512, 2) void down_kernel(
    const bf16_t* __restrict__ h_buf, const float* __restrict__ dwn,
    const int* __restrict__ counts, const int* __restrict__ offsets,
    const int* __restrict__ tok_list, const float* __restrict__ w_list,
    float* __restrict__ out)
{
    const int idx = blockIdx.x;
    const int q = idx & 7;
    const int mslot = (idx >> 3) & 15;
    const int e = idx >> 7;
    const int cnt = counts[e];
    const int mbase = mslot * 256;
    if (mbase >= cnt) return;
    const int nbase = q * 256;
    const int off_e = offsets[e];

    __shared__ __align__(16) bf16_t lds_a[2][256 * 64];
    __shared__ __align__(16) bf16_t lds_w[2][256 * 64];

    const int tid = threadIdx.x;
    const int lane = tid & 63;
    const int w = tid >> 6;
    const int wm = (w >> 2) * 128;
    const int wn = (w & 3) * 64;
    const int l15 = lane & 15;
    const int l4 = lane >> 4;

    const bf16_t* a_src[4];
    int a_doff[4];
#pragma unroll
    for (int j = 0; j < 4; j++) {
        int row = (w * 4 + j) * 8 + (lane >> 3);
        int c8 = (lane & 7) ^ (row & 7);
        int slot = mbase + row;
        int hrow = off_e + (slot < cnt ? slot : cnt - 1);
        a_src[j] = h_buf + (size_t)hrow * DFF + c8 * 8;
        a_doff[j] = (w * 4 + j) * 512;
    }
    const float* w_src[4];
    int w_st[4];
    const float* dwn_e = dwn + (size_t)e * DMODEL * DFF;
#pragma unroll
    for (int c4 = 0; c4 < 4; c4++) {
        int cid = c4 * 512 + tid;
        int row = cid >> 3, c = cid & 7;
        w_src[c4] = dwn_e + (size_t)(nbase + row) * DFF + c * 8;
        w_st[c4] = row * 64 + ((c ^ (row & 7)) * 8);
    }

    fx4 acc[8][4] = {};
    fx4 wreg[8];

    const int NT = DFF / 64;

#pragma unroll
    for (int j = 0; j < 4; j++) gload16(a_src[j], &lds_a[0][a_doff[j]]);
#pragma unroll
    for (int c4 = 0; c4 < 4; c4++) {
        wreg[2 * c4]     = *(const fx4*)(w_src[c4]);
        wreg[2 * c4 + 1] = *(const fx4*)(w_src[c4] + 4);
    }
#pragma unroll
    for (int c4 = 0; c4 < 4; c4++)
        *(bf16x8*)(&lds_w[0][w_st[c4]]) = pack8(wreg[2 * c4], wreg[2 * c4 + 1]);
    asm volatile("s_waitcnt vmcnt(0) lgkmcnt(0)" ::: "memory");
    __builtin_amdgcn_s_barrier();

    for (int t = 0; t < NT; ++t) {
        const int cur = t & 1;
        const int nxt = cur ^ 1;
        const bf16_t* A = lds_a[cur];
        const bf16_t* Wl = lds_w[cur];
        const bool pre = (t + 1 < NT);

        bf16x8 af[2][4], bf0[2][2], bf1[2][2];

        // ---- P1: issue stage(t+1); read A-mh0 + b-nh0; MFMA mh0 x nh0 ----
        if (pre) {
#pragma unroll
            for (int j = 0; j < 4; j++)
                gload16(a_src[j] + (t + 1) * 64, &lds_a[nxt][a_doff[j]]);
#pragma unroll
            for (int c4 = 0; c4 < 4; c4++) {
                wreg[2 * c4]     = *(const fx4*)(w_src[c4] + (t + 1) * 64);
                wreg[2 * c4 + 1] = *(const fx4*)(w_src[c4] + (t + 1) * 64 + 4);
            }
        }
#pragma unroll
        for (int kp = 0; kp < 2; kp++) {
            const int ke = kp * 4 + l4;
#pragma unroll
            for (int m = 0; m < 4; m++) {
                int r = wm + m * 16 + l15;
                af[kp][m] = *(const bf16x8*)(&A[r * 64 + ((ke ^ (r & 7)) * 8)]);
            }
#pragma unroll
            for (int n = 0; n < 2; n++) {
                int r = wn + n * 16 + l15;
                bf0[kp][n] = *(const bf16x8*)(&Wl[r * 64 + ((ke ^ (r & 7)) * 8)]);
            }
        }
        PHASE_SYNC();
        __builtin_amdgcn_s_setprio(1);
#pragma unroll
        for (int kp = 0; kp < 2; kp++)
#pragma unroll
            for (int m = 0; m < 4; m++)
#pragma unroll
                for (int n = 0; n < 2; n++)
                    acc[m][n] = __builtin_amdgcn_mfma_f32_16x16x32_bf16(af[kp][m], bf0[kp][n], acc[m][n], 0, 0, 0);
        __builtin_amdgcn_s_setprio(0);
        __builtin_amdgcn_s_barrier();

        // ---- P2: read b-nh1; MFMA mh0 x nh1 ----
#pragma unroll
        for (int kp = 0; kp < 2; kp++) {
            const int ke = kp * 4 + l4;
#pragma unroll
            for (int n = 0; n < 2; n++) {
                int r = wn + 32 + n * 16 + l15;
                bf1[kp][n] = *(const bf16x8*)(&Wl[r * 64 + ((ke ^ (r & 7)) * 8)]);
            }
        }
        PHASE_SYNC();
        __builtin_amdgcn_s_setprio(1);
#pragma unroll
        for (int kp = 0; kp < 2; kp++)
#pragma unroll
            for (int m = 0; m < 4; m++)
#pragma unroll
                for (int n = 0; n < 2; n++)
                    acc[m][2 + n] = __builtin_amdgcn_mfma_f32_16x16x32_bf16(af[kp][m], bf1[kp][n], acc[m][2 + n], 0, 0, 0);
        __builtin_amdgcn_s_setprio(0);
        __builtin_amdgcn_s_barrier();

        // ---- P3: read A-mh1; MFMA mh1 x nh0 ----
#pragma unroll
        for (int kp = 0; kp < 2; kp++) {
            const int ke = kp * 4 + l4;
#pragma unroll
            for (int m = 0; m < 4; m++) {
                int r = wm + 64 + m * 16 + l15;
                af[kp][m] = *(const bf16x8*)(&A[r * 64 + ((ke ^ (r & 7)) * 8)]);
            }
        }
        PHASE_SYNC();
        __builtin_amdgcn_s_setprio(1);
#pragma unroll
        for (int kp = 0; kp < 2; kp++)
#pragma unroll
            for (int m = 0; m < 4; m++)
#pragma unroll
                for (int n = 0; n < 2; n++)
                    acc[4 + m][n] = __builtin_amdgcn_mfma_f32_16x16x32_bf16(af[kp][m], bf0[kp][n], acc[4 + m][n], 0, 0, 0);
        __builtin_amdgcn_s_setprio(0);
        __builtin_amdgcn_s_barrier();

        // ---- P4: MFMA mh1 x nh1; write-late W(t+1) ----
        __builtin_amdgcn_s_setprio(1);
#pragma unroll
        for (int kp = 0; kp < 2; kp++)
#pragma unroll
            for (int m = 0; m < 4; m++)
#pragma unroll
                for (int n = 0; n < 2; n++)
                    acc[4 + m][2 + n] = __builtin_amdgcn_mfma_f32_16x16x32_bf16(af[kp][m], bf1[kp][n], acc[4 + m][2 + n], 0, 0, 0);
        __builtin_amdgcn_s_setprio(0);
        __builtin_amdgcn_sched_barrier(0);
        if (pre) {
#pragma unroll
            for (int c4 = 0; c4 < 4; c4++)
                *(bf16x8*)(&lds_w[nxt][w_st[c4]]) = pack8(wreg[2 * c4], wreg[2 * c4 + 1]);
        } else {
            asm volatile("s_waitcnt vmcnt(0)" ::: "memory");
        }
        asm volatile("s_waitcnt lgkmcnt(0)" ::: "memory");
        __builtin_amdgcn_s_barrier();
    }

    const int colb = nbase + wn + l15;
#pragma unroll
    for (int am = 0; am < 8; am++) {
        int rb = wm + (am >> 2) * 64 + (am & 3) * 16 + l4 * 4;
#pragma unroll
        for (int j = 0; j < 4; j++) {
            int slot = mbase + rb + j;
            if (slot < cnt) {
                int tok = tok_list[e * T_TOK + slot];
                float wgt = w_list[e * T_TOK + slot];
#pragma unroll
                for (int an = 0; an < 4; an++)
                    atomicAdd(&out[(size_t)tok * DMODEL + colb + (an >> 1) * 32 + (an & 1) * 16], wgt * acc[am][an][j]);
            }
        }
    }
}

// ---------------- launch ----------------
extern "C" void kernel_launch(void* const* d_in, const int* in_sizes, int n_in,
                              void* d_out, int out_size, void* d_ws, size_t ws_size,
                              hipStream_t stream) {
    const float* x      = (const float*)d_in[0];
    const float* gating = (const float*)d_in[1];
    const float* gup    = (const float*)d_in[2];
    const float* dwn    = (const float*)d_in[3];
    float* out = (float*)d_out;

    char* ws = (char*)d_ws;
    int*    counts   = (int*)(ws + 0);
    int*    offsets  = (int*)(ws + 64);
    int*    tok_list = (int*)(ws + 128);
    float*  w_list   = (float*)(ws + 128 + 131072);
    bf16_t* xb       = (bf16_t*)(ws + 262400);
    bf16_t* h_buf    = (bf16_t*)(ws + 17039872);

    hipMemsetAsync(counts, 0, 64, stream);
    hipMemsetAsync(out, 0, (size_t)out_size * sizeof(float), stream);

    router_kernel<<<dim3(T_TOK / 256), dim3(256), 0, stream>>>(gating, counts, tok_list, w_list);
    scan_kernel<<<dim3(1), dim3(64), 0, stream>>>(counts, offsets);
    cvt_x_kernel<<<dim3(T_TOK * DMODEL / 8 / 256), dim3(256), 0, stream>>>(x, xb);

    // 8 e * 8 ygrp * 16 m-slots * 8 XCD = 8192 blocks
    gateup_kernel<<<dim3(8192), dim3(512), 0, stream>>>(
        xb, gup, counts, offsets, tok_list, h_buf);

    // 8 e * 16 m-slots * 8 XCD = 1024 blocks
    down_kernel<<<dim3(1024), dim3(512), 0, stream>>>(
        h_buf, dwn, counts, offsets, tok_list, w_list, out);
}

// Round 13
// 1791.393 us; speedup vs baseline: 1.1782x; 1.1782x over previous
//
#include <hip/hip_runtime.h>
#include <hip/hip_bf16.h>
#include <cstdint>
#include <cstddef>

#define T_TOK 4096
#define DMODEL 2048
#define DFF 8192
#define NEXP 8
#define NPAIR (T_TOK * 2)

typedef __bf16 bf16_t;
typedef __bf16 bf16x8 __attribute__((ext_vector_type(8)));
typedef float fx4 __attribute__((ext_vector_type(4)));
typedef float fx16 __attribute__((ext_vector_type(16)));

__device__ __forceinline__ void gload16(const bf16_t* src, bf16_t* dst) {
    __builtin_amdgcn_global_load_lds(
        (const __attribute__((address_space(1))) uint32_t*)(src),
        (__attribute__((address_space(3))) uint32_t*)(dst), 16, 0, 0);
}

__device__ __forceinline__ bf16x8 pack8(const fx4 lo, const fx4 hi) {
    bf16x8 o;
    o[0] = (bf16_t)lo[0]; o[1] = (bf16_t)lo[1]; o[2] = (bf16_t)lo[2]; o[3] = (bf16_t)lo[3];
    o[4] = (bf16_t)hi[0]; o[5] = (bf16_t)hi[1]; o[6] = (bf16_t)hi[2]; o[7] = (bf16_t)hi[3];
    return o;
}

// rotated XOR swizzle: conflict-free for 32-consecutive-row fragment reads.
// p(c,r) = ((c ^ (r&7)) + 2*((r>>3)&3)) & 7 ; bijective in c per row.
__device__ __forceinline__ int swz(int c, int r) {
    return ((c ^ (r & 7)) + 2 * ((r >> 3) & 3)) & 7;
}
// inverse (for gload_lds source pre-swizzle): given physical chunk pc, logical c:
__device__ __forceinline__ int iswz(int pc, int r) {
    return ((pc - 2 * ((r >> 3) & 3)) & 7) ^ (r & 7);
}

// ---------------- router ----------------
__global__ void router_kernel(const float* __restrict__ gating, int* __restrict__ counts,
                              int* __restrict__ tok_list, float* __restrict__ w_list) {
    int t = blockIdx.x * blockDim.x + threadIdx.x;
    if (t >= T_TOK) return;
    float l[NEXP];
    float mx = -1e30f;
#pragma unroll
    for (int e = 0; e < NEXP; e++) { l[e] = gating[t * NEXP + e]; mx = fmaxf(mx, l[e]); }
#pragma unroll
    for (int e = 0; e < NEXP; e++) { l[e] = __expf(l[e] - mx); }
    int e0 = 0; float p0 = l[0];
#pragma unroll
    for (int e = 1; e < NEXP; e++) { if (l[e] > p0) { p0 = l[e]; e0 = e; } }
    int e1 = -1; float p1 = -1.0f;
#pragma unroll
    for (int e = 0; e < NEXP; e++) { if (e != e0 && l[e] > p1) { p1 = l[e]; e1 = e; } }
    float inv = 1.0f / (p0 + p1);
    int s0 = atomicAdd(&counts[e0], 1);
    tok_list[e0 * T_TOK + s0] = t; w_list[e0 * T_TOK + s0] = p0 * inv;
    int s1 = atomicAdd(&counts[e1], 1);
    tok_list[e1 * T_TOK + s1] = t; w_list[e1 * T_TOK + s1] = p1 * inv;
}

__global__ void scan_kernel(const int* __restrict__ counts, int* __restrict__ offsets) {
    if (threadIdx.x == 0 && blockIdx.x == 0) {
        int acc = 0;
        for (int e = 0; e < NEXP; e++) { offsets[e] = acc; acc += counts[e]; }
        offsets[NEXP] = acc;
    }
}

// ---------------- x fp32 -> bf16 ----------------
__global__ void cvt_x_kernel(const float* __restrict__ x, bf16_t* __restrict__ xb) {
    int i = blockIdx.x * blockDim.x + threadIdx.x;
    const fx4* src = (const fx4*)x;
    fx4 v0 = src[2 * i], v1 = src[2 * i + 1];
    *(bf16x8*)(xb + (size_t)i * 8) = pack8(v0, v1);
}

// ================= gate_up GEMM (R5 schedule, 32x32x16 MFMA) =================
// 512 thr = 8 waves (4M x 2C). tile: M=256 tok x 64 h-cols (W: 64 g + 64 u rows), BK=64.
// wave: 64M x 32h dual acc via 32x32 blocks: accg[2] + accu[2] (fx16) = 64 acc regs.
// A: global_load_lds w=16 (pre-swizzled source). W: fp32 vec-load -> bf16 -> swizzled ds_write.
// Plain 2-barrier loop (TLP-hidden), ~3 blocks/CU.
// dispatch: idx=(g2<<7)|(m<<3)|q : q=XCD, m=mslot(16), g2=(e<<4)|ygrp, panel y=q+8*ygrp.
__global__ __launch_bounds__(512, 4) void gateup_kernel(
    const bf16_t* __restrict__ xb, const float* __restrict__ gup,
    const int* __restrict__ counts, const int* __restrict__ offsets,
    const int* __restrict__ tok_list, bf16_t* __restrict__ h_buf)
{
    const int idx = blockIdx.x;
    const int q = idx & 7;
    const int mslot = (idx >> 3) & 15;
    const int g2 = idx >> 7;             // 0..127
    const int e = g2 >> 4;
    const int cnt = counts[e];
    const int mbase = mslot * 256;
    if (mbase >= cnt) return;
    const int y = q + 8 * (g2 & 15);     // panel 0..127
    const int nb = y * 64;
    const int off_e = offsets[e];

    __shared__ __align__(16) bf16_t lds_a[256 * 64];   // 32 KB
    __shared__ __align__(16) bf16_t lds_w[128 * 64];   // 16 KB (rows 0-63 g, 64-127 u)

    const int tid = threadIdx.x;
    const int lane = tid & 63;
    const int w = tid >> 6;
    const int wm = (w >> 1) * 64;
    const int wc = (w & 1);
    const int l31 = lane & 31;
    const int l32 = lane >> 5;

    // A staging: 4 gload16 per wave, 8 rows per instr, inverse-swizzled source
    const bf16_t* a_src[4];
    int a_doff[4];
#pragma unroll
    for (int j = 0; j < 4; j++) {
        int row = (w * 4 + j) * 8 + (lane >> 3);
        int cs = iswz(lane & 7, row);
        int slot = mbase + row;
        int tok = tok_list[e * T_TOK + (slot < cnt ? slot : cnt - 1)];
        a_src[j] = xb + (size_t)tok * DMODEL + cs * 8;
        a_doff[j] = (w * 4 + j) * 512;
    }
    // W staging: 1024 8-float chunks (128 rows x 8), 2 per thread, swizzled ds_write
    const float* w_src[2];
    int w_st[2];
    const float* gup_e = gup + (size_t)e * (2 * DFF) * DMODEL;
#pragma unroll
    for (int t = 0; t < 2; t++) {
        int cid = t * 512 + tid;
        int row = cid >> 3, c = cid & 7;
        int grow = (row < 64) ? (nb + row) : (DFF + nb + (row - 64));
        w_src[t] = gup_e + (size_t)grow * DMODEL + c * 8;
        w_st[t] = row * 64 + swz(c, row) * 8;
    }

    fx16 accg[2] = {};
    fx16 accu[2] = {};

    // per-thread fragment rows (fixed)
    const int ra0 = wm + l31;
    const int ra1 = wm + 32 + l31;
    const int rg  = wc * 32 + l31;
    const int ru  = 64 + rg;

    for (int k0 = 0; k0 < DMODEL; k0 += 64) {
#pragma unroll
        for (int j = 0; j < 4; j++) gload16(a_src[j] + k0, &lds_a[a_doff[j]]);
#pragma unroll
        for (int t = 0; t < 2; t++) {
            fx4 lo = *(const fx4*)(w_src[t] + k0);
            fx4 hi = *(const fx4*)(w_src[t] + k0 + 4);
            *(bf16x8*)(&lds_w[w_st[t]]) = pack8(lo, hi);
        }
        __syncthreads();
#pragma unroll
        for (int ks = 0; ks < 4; ks++) {
            const int c = ks * 2 + l32;
            bf16x8 a0 = *(const bf16x8*)(&lds_a[ra0 * 64 + swz(c, ra0) * 8]);
            bf16x8 a1 = *(const bf16x8*)(&lds_a[ra1 * 64 + swz(c, ra1) * 8]);
            bf16x8 gf = *(const bf16x8*)(&lds_w[rg * 64 + swz(c, rg) * 8]);
            bf16x8 uf = *(const bf16x8*)(&lds_w[ru * 64 + swz(c, ru) * 8]);
            accg[0] = __builtin_amdgcn_mfma_f32_32x32x16_bf16(a0, gf, accg[0], 0, 0, 0);
            accu[0] = __builtin_amdgcn_mfma_f32_32x32x16_bf16(a0, uf, accu[0], 0, 0, 0);
            accg[1] = __builtin_amdgcn_mfma_f32_32x32x16_bf16(a1, gf, accg[1], 0, 0, 0);
            accu[1] = __builtin_amdgcn_mfma_f32_32x32x16_bf16(a1, uf, accu[1], 0, 0, 0);
        }
        __syncthreads();
    }

    // epilogue: h = silu(g) * u -> bf16. 32x32 C/D: col=lane&31, row=(r&3)+8*(r>>2)+4*(lane>>5)
    const int col = nb + wc * 32 + l31;
#pragma unroll
    for (int m = 0; m < 2; m++) {
#pragma unroll
        for (int r = 0; r < 16; r++) {
            int row = wm + m * 32 + (r & 3) + 8 * (r >> 2) + 4 * l32;
            int slot = mbase + row;
            if (slot < cnt) {
                float g = accg[m][r];
                float u = accu[m][r];
                float hv = g * u / (1.0f + __expf(-g));
                h_buf[(size_t)(off_e + slot) * DFF + col] = (bf16_t)hv;
            }
        }
    }
}

// ================= down GEMM (R5 schedule, 32x32x16 MFMA) =================
// 512 thr = 8 waves (4M x 2N). tile M=256 pairs x 128 out-cols, BK=64, 128 K-steps.
// wave 64x64 via 2x2 32x32 blocks: acc[2][2] fx16 = 64 acc regs.
// dispatch: idx=(e<<8)|(pp<<7)|(m<<3)|q : panel y=q+8*pp (16 panels of 128 cols)
__global__ __launch_bounds__(512, 4) void down_kernel(
    const bf16_t* __restrict__ h_buf, const float* __restrict__ dwn,
    const int* __restrict__ counts, const int* __restrict__ offsets,
    const int* __restrict__ tok_list, const float* __restrict__ w_list,
    float* __restrict__ out)
{
    const int idx = blockIdx.x;
    const int q = idx & 7;
    const int mslot = (idx >> 3) & 15;
    const int rest = idx >> 7;
    const int pp = rest & 1;
    const int e = rest >> 1;
    const int cnt = counts[e];
    const int mbase = mslot * 256;
    if (mbase >= cnt) return;
    const int y = q + 8 * pp;          // 0..15
    const int nbase = y * 128;
    const int off_e = offsets[e];

    __shared__ __align__(16) bf16_t lds_a[256 * 64];   // 32 KB
    __shared__ __align__(16) bf16_t lds_w[128 * 64];   // 16 KB

    const int tid = threadIdx.x;
    const int lane = tid & 63;
    const int w = tid >> 6;
    const int wm = (w >> 1) * 64;
    const int wn = (w & 1) * 64;
    const int l31 = lane & 31;
    const int l32 = lane >> 5;

    const bf16_t* a_src[4];
    int a_doff[4];
#pragma unroll
    for (int j = 0; j < 4; j++) {
        int row = (w * 4 + j) * 8 + (lane >> 3);
        int cs = iswz(lane & 7, row);
        int slot = mbase + row;
        int hrow = off_e + (slot < cnt ? slot : cnt - 1);
        a_src[j] = h_buf + (size_t)hrow * DFF + cs * 8;
        a_doff[j] = (w * 4 + j) * 512;
    }
    const float* w_src[2];
    int w_st[2];
    const float* dwn_e = dwn + (size_t)e * DMODEL * DFF;
#pragma unroll
    for (int t = 0; t < 2; t++) {
        int cid = t * 512 + tid;
        int row = cid >> 3, c = cid & 7;
        w_src[t] = dwn_e + (size_t)(nbase + row) * DFF + c * 8;
        w_st[t] = row * 64 + swz(c, row) * 8;
    }

    fx16 acc[2][2] = {};

    const int ra0 = wm + l31;
    const int ra1 = wm + 32 + l31;
    const int rb0 = wn + l31;
    const int rb1 = wn + 32 + l31;

    for (int k0 = 0; k0 < DFF; k0 += 64) {
#pragma unroll
        for (int j = 0; j < 4; j++) gload16(a_src[j] + k0, &lds_a[a_doff[j]]);
#pragma unroll
        for (int t = 0; t < 2; t++) {
            fx4 lo = *(const fx4*)(w_src[t] + k0);
            fx4 hi = *(const fx4*)(w_src[t] + k0 + 4);
            *(bf16x8*)(&lds_w[w_st[t]]) = pack8(lo, hi);
        }
        __syncthreads();
#pragma unroll
        for (int ks = 0; ks < 4; ks++) {
            const int c = ks * 2 + l32;
            bf16x8 a0 = *(const bf16x8*)(&lds_a[ra0 * 64 + swz(c, ra0) * 8]);
            bf16x8 a1 = *(const bf16x8*)(&lds_a[ra1 * 64 + swz(c, ra1) * 8]);
            bf16x8 b0 = *(const bf16x8*)(&lds_w[rb0 * 64 + swz(c, rb0) * 8]);
            bf16x8 b1 = *(const bf16x8*)(&lds_w[rb1 * 64 + swz(c, rb1) * 8]);
            acc[0][0] = __builtin_amdgcn_mfma_f32_32x32x16_bf16(a0, b0, acc[0][0], 0, 0, 0);
            acc[0][1] = __builtin_amdgcn_mfma_f32_32x32x16_bf16(a0, b1, acc[0][1], 0, 0, 0);
            acc[1][0] = __builtin_amdgcn_mfma_f32_32x32x16_bf16(a1, b0, acc[1][0], 0, 0, 0);
            acc[1][1] = __builtin_amdgcn_mfma_f32_32x32x16_bf16(a1, b1, acc[1][1], 0, 0, 0);
        }
        __syncthreads();
    }

    // epilogue: out[tok][col] += wgt * acc ; col=lane&31 within 32-block
#pragma unroll
    for (int m = 0; m < 2; m++) {
#pragma unroll
        for (int r = 0; r < 16; r++) {
            int row = wm + m * 32 + (r & 3) + 8 * (r >> 2) + 4 * l32;
            int slot = mbase + row;
            if (slot < cnt) {
                int tok = tok_list[e * T_TOK + slot];
                float wgt = w_list[e * T_TOK + slot];
#pragma unroll
                for (int n = 0; n < 2; n++) {
                    int col = nbase + wn + n * 32 + l31;
                    atomicAdd(&out[(size_t)tok * DMODEL + col], wgt * acc[m][n][r]);
                }
            }
        }
    }
}

// ---------------- launch ----------------
extern "C" void kernel_launch(void* const* d_in, const int* in_sizes, int n_in,
                              void* d_out, int out_size, void* d_ws, size_t ws_size,
                              hipStream_t stream) {
    const float* x      = (const float*)d_in[0];
    const float* gating = (const float*)d_in[1];
    const float* gup    = (const float*)d_in[2];
    const float* dwn    = (const float*)d_in[3];
    float* out = (float*)d_out;

    char* ws = (char*)d_ws;
    int*    counts   = (int*)(ws + 0);
    int*    offsets  = (int*)(ws + 64);
    int*    tok_list = (int*)(ws + 128);
    float*  w_list   = (float*)(ws + 128 + 131072);
    bf16_t* xb       = (bf16_t*)(ws + 262400);
    bf16_t* h_buf    = (bf16_t*)(ws + 17039872);

    hipMemsetAsync(counts, 0, 64, stream);
    hipMemsetAsync(out, 0, (size_t)out_size * sizeof(float), stream);

    router_kernel<<<dim3(T_TOK / 256), dim3(256), 0, stream>>>(gating, counts, tok_list, w_list);
    scan_kernel<<<dim3(1), dim3(64), 0, stream>>>(counts, offsets);
    cvt_x_kernel<<<dim3(T_TOK * DMODEL / 8 / 256), dim3(256), 0, stream>>>(x, xb);

    // 128 g2 (e,ygrp) * 16 m-slots * 8 XCD-slots = 16384 blocks
    gateup_kernel<<<dim3(16384), dim3(512), 0, stream>>>(
        xb, gup, counts, offsets, tok_list, h_buf);

    // 8 e * 2 pp * 16 m-slots * 8 XCD-slots = 2048 blocks
    down_kernel<<<dim3(2048), dim3(512), 0, stream>>>(
        h_buf, dwn, counts, offsets, tok_list, w_list, out);
}